// Round 8
// baseline (212.376 us; speedup 1.0000x reference)
//
#include <hip/hip_runtime.h>

#define EPS 1e-12f

// problem sizes
#define BATCH 4
#define CIN   768
#define LIN   4096
#define DCODE 128
#define TOUT  2048
#define NROWS (BATCH*TOUT)   // 8192
#define KCB   8192
#define KCONV 2304           // 3*768, k = j*768 + c (j-major)

// ws layout (bytes) — total ~68.6 MB
#define OFF_CN2  0u          // 8192 f32
#define OFF_BS   32768u      // 2*8192 f32
#define OFF_BI   163840u     // 2*8192 i32
#define OFF_EH   294912u     // 8192*128 f16
#define OFF_EL   2392064u
#define OFF_CH   4489216u
#define OFF_CL   6586368u
#define OFF_WHT  8683520u    // 128*2304 f16 = 589,824
#define OFF_WLT  9273344u
#define OFF_PART 9863168u    // 2*8192*128 f32 = 8,388,608
#define OFF_XTH  18251776u   // 4*4096*768 f16 = 25,165,824
#define OFF_XTL  43417600u   // end 68,583,424

typedef _Float16 half_t;
typedef __attribute__((ext_vector_type(8))) _Float16 half8;
typedef __attribute__((ext_vector_type(2))) _Float16 half2v;
typedef __attribute__((ext_vector_type(4))) float f32x4;

// ---------------------------------------------------------------------------
// Weights -> fp16 hi/lo, layout wT[n][k], k = j*768 + c.
__global__ __launch_bounds__(256) void k_wt2(const float* __restrict__ w,
                                             half_t* __restrict__ wht,
                                             half_t* __restrict__ wlt) {
    int k = blockIdx.x * 256 + threadIdx.x;
    int n = blockIdx.y;
    if (k >= KCONV) return;
    int j = (k >= 1536) ? 2 : (k >= 768) ? 1 : 0;
    int c = k - j * 768;
    float v = w[(size_t)n * KCONV + c * 3 + j];
    half_t h = (half_t)v;
    wht[(size_t)n * KCONV + k] = h;
    wlt[(size_t)n * KCONV + k] = (half_t)(v - (float)h);
}

// ---------------------------------------------------------------------------
// Transpose x[b][c][s] -> xt[b][s][c] as fp16 hi/lo (LDS 32x33 tile).
__global__ __launch_bounds__(256) void k_xt(const float* __restrict__ x,
                                            half_t* __restrict__ xth,
                                            half_t* __restrict__ xtl) {
    __shared__ float tile[32][33];
    const int s0 = blockIdx.x * 32;
    const int c0 = blockIdx.y * 32;
    const int b  = blockIdx.z;
    const int sl = threadIdx.x & 31;
    const int cl = threadIdx.x >> 5;
    const float* xg = x + ((size_t)b * CIN + c0) * LIN + s0;
    #pragma unroll
    for (int p = 0; p < 4; ++p) {
        int c = cl + p * 8;
        tile[c][sl] = xg[(size_t)c * LIN + sl];
    }
    __syncthreads();
    const int wcc = (threadIdx.x & 15) * 2;
    const int wss = threadIdx.x >> 4;
    #pragma unroll
    for (int p = 0; p < 2; ++p) {
        int s = wss + p * 16;
        float v0 = tile[wcc][s], v1 = tile[wcc + 1][s];
        half_t h0 = (half_t)v0, h1 = (half_t)v1;
        half_t l0 = (half_t)(v0 - (float)h0), l1 = (half_t)(v1 - (float)h1);
        size_t o = ((size_t)b * LIN + s0 + s) * CIN + c0 + wcc;
        *(half2v*)(xth + o) = half2v{h0, h1};
        *(half2v*)(xtl + o) = half2v{l0, l1};
    }
}

// ---------------------------------------------------------------------------
// Normalize codebook rows -> fp16 hi/lo split; cn2[k] = ||c_norm||^2.
__global__ __launch_bounds__(256) void k_cbnorm(const float* __restrict__ cb,
                                                half_t* __restrict__ ch,
                                                half_t* __restrict__ cl,
                                                float* __restrict__ cn2) {
    int wid  = threadIdx.x >> 6;
    int lane = threadIdx.x & 63;
    int k = blockIdx.x * 4 + wid;
    const float2* src = (const float2*)cb + (size_t)k * 64;
    float2 v = src[lane];
    float ss = v.x * v.x + v.y * v.y;
    #pragma unroll
    for (int m = 1; m < 64; m <<= 1) ss += __shfl_xor(ss, m);
    float inv = 1.0f / fmaxf(sqrtf(ss), EPS);
    float nx = v.x * inv, ny = v.y * inv;
    half_t hx = (half_t)nx, hy = (half_t)ny;
    half_t lx = (half_t)(nx - (float)hx), ly = (half_t)(ny - (float)hy);
    ((half2v*)ch)[(size_t)k * 64 + lane] = half2v{hx, hy};
    ((half2v*)cl)[(size_t)k * 64 + lane] = half2v{lx, ly};
    if (lane == 0) cn2[k] = ss * inv * inv;
}

// ---------------------------------------------------------------------------
// Conv as MFMA GEMM — 512 thr (8 waves = 2 row-groups x 4 col-groups)
// -> 2 waves/SIMD so VALU/LDS/staging of one wave hides under the other's MFMA.
__global__ __launch_bounds__(512, 2) void k_conv_mfma(
        const half_t* __restrict__ xth, const half_t* __restrict__ xtl,
        const half_t* __restrict__ wht, const half_t* __restrict__ wlt,
        float* __restrict__ part) {
    extern __shared__ char smem[];   // 2 x (32KB hi + 32KB lo)
    const int tid  = threadIdx.x;
    const int lane = tid & 63;
    const int w    = tid >> 6;       // 0..7
    const int rg   = w >> 2;         // row-group (32 rows)
    const int cgw  = w & 3;          // col-group (32 cols)
    const int lr   = lane & 15;
    const int lg   = lane >> 4;
    const int r0   = blockIdx.x * 64;
    const int ks   = blockIdx.y;
    const int b    = r0 >> 11;
    const int t00  = r0 & 2047;
    const int kbase = ks * 1152;

    // staging: waves 0-3 stage hi (32 cols each), 4-7 stage lo
    const half_t* msrc = (w >= 4) ? wlt : wht;
    const int wmod = w & 3;
    auto stage = [&](int t, int buf) {
        int k0 = kbase + t * 128;
        #pragma unroll
        for (int i = 0; i < 8; ++i) {
            int col_l = wmod * 32 + i * 4 + lg;
            int ksrc  = (lr * 16) ^ ((col_l & 7) << 4);   // inverse swizzle
            const char* g = (const char*)msrc + (size_t)col_l * 4608
                          + (size_t)k0 * 2 + ksrc;
            char* l = smem + buf * 65536 + (w >> 2) * 32768 + wmod * 8192
                    + i * 1024;  // +lane*16 HW
            __builtin_amdgcn_global_load_lds(
                (const __attribute__((address_space(1))) void*)(uintptr_t)g,
                (__attribute__((address_space(3))) void*)(uintptr_t)l, 16, 0, 0);
        }
    };

    f32x4 acc[2][2];
    #pragma unroll
    for (int g = 0; g < 2; ++g)
        #pragma unroll
        for (int cg = 0; cg < 2; ++cg) acc[g][cg] = f32x4{0.f, 0.f, 0.f, 0.f};

    stage(0, 0);
    __syncthreads();

    int buf = 0;
    for (int t = 0; t < 9; ++t) {
        int k0 = kbase + t * 128;
        int j  = (k0 >= 1536) ? 2 : (k0 >= 768) ? 1 : 0;
        int c0 = k0 - j * 768;
        half8 ah[2][4], al[2][4];
        #pragma unroll
        for (int g = 0; g < 2; ++g) {
            int trow = t00 + rg * 32 + g * 16 + lr;
            int s = 2 * trow - 1 + j;
            bool valid = (unsigned)s < (unsigned)LIN;
            size_t o = ((size_t)b * LIN + (valid ? s : 0)) * CIN + c0 + lg * 8;
            const half8* ph = (const half8*)(xth + o);
            const half8* pl = (const half8*)(xtl + o);
            #pragma unroll
            for (int kc = 0; kc < 4; ++kc) {
                half8 vh = {}, vl = {};
                if (valid) { vh = ph[kc * 4]; vl = pl[kc * 4]; }
                ah[g][kc] = vh; al[g][kc] = vl;
            }
        }
        if (t < 8) stage(t + 1, buf ^ 1);
        const char* bhp = smem + buf * 65536;
        const char* blp = bhp + 32768;
        #pragma unroll
        for (int kc = 0; kc < 4; ++kc) {
            half8 bhf[2], blf[2];
            #pragma unroll
            for (int cg = 0; cg < 2; ++cg) {
                int col   = cgw * 32 + cg * 16 + lr;
                int kswz  = (col & 7) << 4;
                int cbyte = col * 256;
                int kb    = (kc * 64 + lg * 16) ^ kswz;
                bhf[cg] = *(const half8*)(bhp + cbyte + kb);
                blf[cg] = *(const half8*)(blp + cbyte + kb);
            }
            #pragma unroll
            for (int cg = 0; cg < 2; ++cg)
                #pragma unroll
                for (int g = 0; g < 2; ++g)
                    acc[g][cg] = __builtin_amdgcn_mfma_f32_16x16x32_f16(ah[g][kc], bhf[cg], acc[g][cg], 0, 0, 0);
            #pragma unroll
            for (int cg = 0; cg < 2; ++cg)
                #pragma unroll
                for (int g = 0; g < 2; ++g)
                    acc[g][cg] = __builtin_amdgcn_mfma_f32_16x16x32_f16(al[g][kc], bhf[cg], acc[g][cg], 0, 0, 0);
            #pragma unroll
            for (int cg = 0; cg < 2; ++cg)
                #pragma unroll
                for (int g = 0; g < 2; ++g)
                    acc[g][cg] = __builtin_amdgcn_mfma_f32_16x16x32_f16(ah[g][kc], blf[cg], acc[g][cg], 0, 0, 0);
        }
        __syncthreads();
        buf ^= 1;
    }

    float* pb = part + (size_t)ks * NROWS * DCODE;
    #pragma unroll
    for (int g = 0; g < 2; ++g)
        #pragma unroll
        for (int cg = 0; cg < 2; ++cg) {
            int col = cgw * 32 + cg * 16 + lr;
            #pragma unroll
            for (int rr = 0; rr < 4; ++rr) {
                int row = r0 + rg * 32 + g * 16 + lg * 4 + rr;
                pb[(size_t)row * DCODE + col] = acc[g][cg][rr];
            }
        }
}

// ---------------------------------------------------------------------------
// Combine K-halves + L2-normalize encodings -> fp16 hi/lo split.
__global__ __launch_bounds__(256) void k_encnorm(const float* __restrict__ part,
                                                 half_t* __restrict__ eh,
                                                 half_t* __restrict__ el) {
    int wid  = threadIdx.x >> 6;
    int lane = threadIdx.x & 63;
    int r = blockIdx.x * 4 + wid;
    const float2* p0 = (const float2*)part + (size_t)r * 64;
    const float2* p1 = (const float2*)(part + (size_t)NROWS * DCODE) + (size_t)r * 64;
    float2 a = p0[lane];
    float2 c = p1[lane];
    a.x += c.x; a.y += c.y;
    float ss = a.x * a.x + a.y * a.y;
    #pragma unroll
    for (int m = 1; m < 64; m <<= 1) ss += __shfl_xor(ss, m);
    float inv = 1.0f / fmaxf(sqrtf(ss), EPS);
    float nx = a.x * inv, ny = a.y * inv;
    half_t hx = (half_t)nx, hy = (half_t)ny;
    half_t lx = (half_t)(nx - (float)hx), ly = (half_t)(ny - (float)hy);
    ((half2v*)eh)[(size_t)r * 64 + lane] = half2v{hx, hy};
    ((half2v*)el)[(size_t)r * 64 + lane] = half2v{lx, ly};
}

// ---------------------------------------------------------------------------
// MFMA dist+argmax — 512 thr (8 waves, 16 cols/wave, A = all 64 rows in regs
// per wave) -> 2 waves/SIMD. blockIdx.y = col HALF (4096 codewords).
// Staging/swizzle/fragment maps identical to the round-4/5 validated kernels.
__global__ __launch_bounds__(512, 2) void k_dist(const half_t* __restrict__ eh,
                                                 const half_t* __restrict__ el,
                                                 const half_t* __restrict__ ch,
                                                 const half_t* __restrict__ cl,
                                                 const float* __restrict__ cn2,
                                                 float* __restrict__ best_s,
                                                 int* __restrict__ best_i) {
    extern __shared__ char smem[];          // 2 x (32KB hi + 32KB lo)
    const int tid  = threadIdx.x;
    const int lane = tid & 63;
    const int w    = tid >> 6;              // 0..7
    const int lr   = lane & 15;
    const int lg   = lane >> 4;
    const int r0   = blockIdx.x * 64;
    const int kqbase = blockIdx.y * 4096;

    // A: all 64 rows per wave, k = kc*32 + lg*8
    half8 ah[4][4], al[4][4];
    #pragma unroll
    for (int g = 0; g < 4; ++g) {
        int row = r0 + g * 16 + lr;
        const half8* ph = (const half8*)(eh + (size_t)row * 128 + lg * 8);
        const half8* pl = (const half8*)(el + (size_t)row * 128 + lg * 8);
        #pragma unroll
        for (int kc = 0; kc < 4; ++kc) { ah[g][kc] = ph[kc * 4]; al[g][kc] = pl[kc * 4]; }
    }

    // staging: waves 0-3 stage hi (32 cols each), 4-7 stage lo
    const half_t* msrc = (w >= 4) ? cl : ch;
    const int wmod = w & 3;
    auto stage = [&](int t, int buf) {
        #pragma unroll
        for (int i = 0; i < 8; ++i) {
            int col_l = wmod * 32 + i * 4 + lg;
            int ksrc  = (lr * 16) ^ ((col_l & 7) << 4);
            const char* g = (const char*)msrc
                          + ((size_t)(kqbase + t * 128 + col_l)) * 256 + ksrc;
            char* l = smem + buf * 65536 + (w >> 2) * 32768 + wmod * 8192
                    + i * 1024;
            __builtin_amdgcn_global_load_lds(
                (const __attribute__((address_space(1))) void*)(uintptr_t)g,
                (__attribute__((address_space(3))) void*)(uintptr_t)l, 16, 0, 0);
        }
    };

    float bs[4][4]; int bi[4][4];
    #pragma unroll
    for (int g = 0; g < 4; ++g)
        #pragma unroll
        for (int rr = 0; rr < 4; ++rr) { bs[g][rr] = -3.4e38f; bi[g][rr] = 0; }

    stage(0, 0);
    __syncthreads();

    int buf = 0;
    for (int t = 0; t < 32; ++t) {
        if (t < 31) stage(t + 1, buf ^ 1);
        int n = kqbase + t * 128 + w * 16 + lr;     // this thread's col
        float cnv = cn2[n];
        const char* bhp = smem + buf * 65536;
        const char* blp = bhp + 32768;
        f32x4 acc[4];
        #pragma unroll
        for (int g = 0; g < 4; ++g) acc[g] = f32x4{0.f, 0.f, 0.f, 0.f};
        const int col   = w * 16 + lr;
        const int kswz  = (col & 7) << 4;
        const int cbyte = col * 256;
        #pragma unroll
        for (int kc = 0; kc < 4; ++kc) {
            int kb = (kc * 64 + lg * 16) ^ kswz;
            half8 bhf = *(const half8*)(bhp + cbyte + kb);
            half8 blf = *(const half8*)(blp + cbyte + kb);
            #pragma unroll
            for (int g = 0; g < 4; ++g)
                acc[g] = __builtin_amdgcn_mfma_f32_16x16x32_f16(ah[g][kc], bhf, acc[g], 0, 0, 0);
            #pragma unroll
            for (int g = 0; g < 4; ++g)
                acc[g] = __builtin_amdgcn_mfma_f32_16x16x32_f16(al[g][kc], bhf, acc[g], 0, 0, 0);
            #pragma unroll
            for (int g = 0; g < 4; ++g)
                acc[g] = __builtin_amdgcn_mfma_f32_16x16x32_f16(ah[g][kc], blf, acc[g], 0, 0, 0);
        }
        #pragma unroll
        for (int g = 0; g < 4; ++g)
            #pragma unroll
            for (int rr = 0; rr < 4; ++rr) {
                float sc = 2.0f * acc[g][rr] - cnv;
                if (sc > bs[g][rr]) { bs[g][rr] = sc; bi[g][rr] = n; }
            }
        __syncthreads();
        buf ^= 1;
    }

    // reduce over the 16 lr lanes (cols within wave), then across 8 waves via LDS
    float* redS = (float*)smem;          // [8][64]
    int*   redI = (int*)(smem + 2048);   // [8][64]
    #pragma unroll
    for (int g = 0; g < 4; ++g)
        #pragma unroll
        for (int rr = 0; rr < 4; ++rr) {
            float s = bs[g][rr]; int i = bi[g][rr];
            #pragma unroll
            for (int m = 1; m < 16; m <<= 1) {
                float os = __shfl_xor(s, m);
                int   oi = __shfl_xor(i, m);
                if (os > s || (os == s && oi < i)) { s = os; i = oi; }
            }
            if (lr == 0) {
                int row = g * 16 + lg * 4 + rr;
                redS[w * 64 + row] = s;
                redI[w * 64 + row] = i;
            }
        }
    __syncthreads();
    if (tid < 64) {
        float s = redS[tid]; int i = redI[tid];
        #pragma unroll
        for (int w2 = 1; w2 < 8; ++w2) {
            float s2 = redS[w2 * 64 + tid];
            int   i2 = redI[w2 * 64 + tid];
            if (s2 > s || (s2 == s && i2 < i)) { s = s2; i = i2; }
        }
        best_s[(size_t)blockIdx.y * NROWS + r0 + tid] = s;
        best_i[(size_t)blockIdx.y * NROWS + r0 + tid] = i;
    }
}

// ---------------------------------------------------------------------------
__global__ __launch_bounds__(256) void k_merge(const float* __restrict__ bs,
                                               const int* __restrict__ bi,
                                               int* __restrict__ out) {
    int r = blockIdx.x * 256 + threadIdx.x;
    if (r >= NROWS) return;
    float s = bs[r]; int i = bi[r];
    #pragma unroll
    for (int q = 1; q < 2; ++q) {
        float s2 = bs[(size_t)q * NROWS + r];
        int   i2 = bi[(size_t)q * NROWS + r];
        if (s2 > s || (s2 == s && i2 < i)) { s = s2; i = i2; }
    }
    out[r] = i;
}

// ---------------------------------------------------------------------------
extern "C" void kernel_launch(void* const* d_in, const int* in_sizes, int n_in,
                              void* d_out, int out_size, void* d_ws, size_t ws_size,
                              hipStream_t stream) {
    const float* x  = (const float*)d_in[0];
    const float* w  = (const float*)d_in[1];
    const float* cb = (const float*)d_in[2];
    char* ws = (char*)d_ws;
    float*  cn2  = (float*)(ws + OFF_CN2);
    float*  bs   = (float*)(ws + OFF_BS);
    int*    bi   = (int*)(ws + OFF_BI);
    half_t* eh   = (half_t*)(ws + OFF_EH);
    half_t* el   = (half_t*)(ws + OFF_EL);
    half_t* chh  = (half_t*)(ws + OFF_CH);
    half_t* cll  = (half_t*)(ws + OFF_CL);
    half_t* wht  = (half_t*)(ws + OFF_WHT);
    half_t* wlt  = (half_t*)(ws + OFF_WLT);
    float*  part = (float*)(ws + OFF_PART);
    half_t* xth  = (half_t*)(ws + OFF_XTH);
    half_t* xtl  = (half_t*)(ws + OFF_XTL);
    int*    out  = (int*)d_out;

    hipFuncSetAttribute((const void*)k_dist,
                        hipFuncAttributeMaxDynamicSharedMemorySize, 131072);
    hipFuncSetAttribute((const void*)k_conv_mfma,
                        hipFuncAttributeMaxDynamicSharedMemorySize, 131072);

    k_wt2     <<<dim3(9, 128), 256, 0, stream>>>(w, wht, wlt);
    k_cbnorm  <<<2048, 256, 0, stream>>>(cb, chh, cll, cn2);
    k_xt      <<<dim3(128, 24, 4), 256, 0, stream>>>(x, xth, xtl);
    k_conv_mfma<<<dim3(128, 2), 512, 131072, stream>>>(xth, xtl, wht, wlt, part);
    k_encnorm <<<2048, 256, 0, stream>>>(part, eh, el);
    k_dist    <<<dim3(128, 2), 512, 131072, stream>>>(eh, el, chh, cll, cn2, bs, bi);
    k_merge   <<<32, 256, 0, stream>>>(bs, bi, out);
}

// Round 9
// 212.319 us; speedup vs baseline: 1.0003x; 1.0003x over previous
//
#include <hip/hip_runtime.h>

#define EPS 1e-12f

// problem sizes
#define BATCH 4
#define CIN   768
#define LIN   4096
#define DCODE 128
#define TOUT  2048
#define NROWS (BATCH*TOUT)   // 8192
#define KCB   8192
#define KCONV 2304           // 3*768, k = j*768 + c (j-major)

// ws layout (bytes) — total ~68.6 MB
#define OFF_CN2  0u          // 8192 f32
#define OFF_BS   32768u      // 2*8192 f32
#define OFF_BI   163840u     // 2*8192 i32
#define OFF_EH   294912u     // 8192*128 f16
#define OFF_EL   2392064u
#define OFF_CH   4489216u
#define OFF_CL   6586368u
#define OFF_WHT  8683520u    // 128*2304 f16 = 589,824
#define OFF_WLT  9273344u
#define OFF_PART 9863168u    // 2*8192*128 f32 = 8,388,608
#define OFF_XTH  18251776u   // 4*4096*768 f16 = 25,165,824
#define OFF_XTL  43417600u   // end 68,583,424

typedef _Float16 half_t;
typedef __attribute__((ext_vector_type(8))) _Float16 half8;
typedef __attribute__((ext_vector_type(2))) _Float16 half2v;
typedef __attribute__((ext_vector_type(4))) float f32x4;

#define VMCNT(n) asm volatile("s_waitcnt vmcnt(" #n ")" ::: "memory")

// ---------------------------------------------------------------------------
// Weights -> fp16 hi/lo, layout wT[n][k], k = j*768 + c.
__global__ __launch_bounds__(256) void k_wt2(const float* __restrict__ w,
                                             half_t* __restrict__ wht,
                                             half_t* __restrict__ wlt) {
    int k = blockIdx.x * 256 + threadIdx.x;
    int n = blockIdx.y;
    if (k >= KCONV) return;
    int j = (k >= 1536) ? 2 : (k >= 768) ? 1 : 0;
    int c = k - j * 768;
    float v = w[(size_t)n * KCONV + c * 3 + j];
    half_t h = (half_t)v;
    wht[(size_t)n * KCONV + k] = h;
    wlt[(size_t)n * KCONV + k] = (half_t)(v - (float)h);
}

// ---------------------------------------------------------------------------
// Transpose x[b][c][s] -> xt[b][s][c] fp16 hi/lo. Round-9: 64s x 128c tiles,
// float4-coalesced loads (16B/lane), LDS transpose, half8 stores (16B/lane).
__global__ __launch_bounds__(256) void k_xt(const float* __restrict__ x,
                                            half_t* __restrict__ xth,
                                            half_t* __restrict__ xtl) {
    __shared__ float tile[128 * 68];     // [c][s], pad 68 (16B-aligned rows)
    const int s0 = blockIdx.x * 64;
    const int c0 = blockIdx.y * 128;
    const int b  = blockIdx.z;
    const int f4  = threadIdx.x & 15;    // 16 x float4 = 64 samples
    const int crb = threadIdx.x >> 4;    // 16 channel groups
    #pragma unroll
    for (int p = 0; p < 8; ++p) {
        int cr = crb + p * 16;
        float4 v = *(const float4*)(x + ((size_t)(b * CIN + c0 + cr)) * LIN + s0 + f4 * 4);
        *(float4*)(tile + cr * 68 + f4 * 4) = v;
    }
    __syncthreads();
    const int sr = threadIdx.x >> 2;     // 0..63 output sample
    const int cq = threadIdx.x & 3;      // 32-channel quarter
    size_t ob = ((size_t)b * LIN + s0 + sr) * CIN + c0 + cq * 32;
    half8 hv[4], lv[4];
    #pragma unroll
    for (int q = 0; q < 4; ++q)
        #pragma unroll
        for (int e = 0; e < 8; ++e) {
            float v = tile[(cq * 32 + q * 8 + e) * 68 + sr];
            half_t h = (half_t)v;
            hv[q][e] = h;
            lv[q][e] = (half_t)(v - (float)h);
        }
    #pragma unroll
    for (int q = 0; q < 4; ++q) {
        *(half8*)(xth + ob + q * 8) = hv[q];
        *(half8*)(xtl + ob + q * 8) = lv[q];
    }
}

// ---------------------------------------------------------------------------
// Normalize codebook rows -> fp16 hi/lo split; cn2[k] = ||c_norm||^2.
__global__ __launch_bounds__(256) void k_cbnorm(const float* __restrict__ cb,
                                                half_t* __restrict__ ch,
                                                half_t* __restrict__ cl,
                                                float* __restrict__ cn2) {
    int wid  = threadIdx.x >> 6;
    int lane = threadIdx.x & 63;
    int k = blockIdx.x * 4 + wid;
    const float2* src = (const float2*)cb + (size_t)k * 64;
    float2 v = src[lane];
    float ss = v.x * v.x + v.y * v.y;
    #pragma unroll
    for (int m = 1; m < 64; m <<= 1) ss += __shfl_xor(ss, m);
    float inv = 1.0f / fmaxf(sqrtf(ss), EPS);
    float nx = v.x * inv, ny = v.y * inv;
    half_t hx = (half_t)nx, hy = (half_t)ny;
    half_t lx = (half_t)(nx - (float)hx), ly = (half_t)(ny - (float)hy);
    ((half2v*)ch)[(size_t)k * 64 + lane] = half2v{hx, hy};
    ((half2v*)cl)[(size_t)k * 64 + lane] = half2v{lx, ly};
    if (lane == 0) cn2[k] = ss * inv * inv;
}

// ---------------------------------------------------------------------------
// Conv as MFMA GEMM — unchanged from validated round 8.
__global__ __launch_bounds__(512, 2) void k_conv_mfma(
        const half_t* __restrict__ xth, const half_t* __restrict__ xtl,
        const half_t* __restrict__ wht, const half_t* __restrict__ wlt,
        float* __restrict__ part) {
    extern __shared__ char smem[];   // 2 x (32KB hi + 32KB lo)
    const int tid  = threadIdx.x;
    const int lane = tid & 63;
    const int w    = tid >> 6;       // 0..7
    const int rg   = w >> 2;         // row-group (32 rows)
    const int cgw  = w & 3;          // col-group (32 cols)
    const int lr   = lane & 15;
    const int lg   = lane >> 4;
    const int r0   = blockIdx.x * 64;
    const int ks   = blockIdx.y;
    const int b    = r0 >> 11;
    const int t00  = r0 & 2047;
    const int kbase = ks * 1152;

    const half_t* msrc = (w >= 4) ? wlt : wht;
    const int wmod = w & 3;
    auto stage = [&](int t, int buf) {
        int k0 = kbase + t * 128;
        #pragma unroll
        for (int i = 0; i < 8; ++i) {
            int col_l = wmod * 32 + i * 4 + lg;
            int ksrc  = (lr * 16) ^ ((col_l & 7) << 4);   // inverse swizzle
            const char* g = (const char*)msrc + (size_t)col_l * 4608
                          + (size_t)k0 * 2 + ksrc;
            char* l = smem + buf * 65536 + (w >> 2) * 32768 + wmod * 8192
                    + i * 1024;  // +lane*16 HW
            __builtin_amdgcn_global_load_lds(
                (const __attribute__((address_space(1))) void*)(uintptr_t)g,
                (__attribute__((address_space(3))) void*)(uintptr_t)l, 16, 0, 0);
        }
    };

    f32x4 acc[2][2];
    #pragma unroll
    for (int g = 0; g < 2; ++g)
        #pragma unroll
        for (int cg = 0; cg < 2; ++cg) acc[g][cg] = f32x4{0.f, 0.f, 0.f, 0.f};

    stage(0, 0);
    __syncthreads();

    int buf = 0;
    for (int t = 0; t < 9; ++t) {
        int k0 = kbase + t * 128;
        int j  = (k0 >= 1536) ? 2 : (k0 >= 768) ? 1 : 0;
        int c0 = k0 - j * 768;
        half8 ah[2][4], al[2][4];
        #pragma unroll
        for (int g = 0; g < 2; ++g) {
            int trow = t00 + rg * 32 + g * 16 + lr;
            int s = 2 * trow - 1 + j;
            bool valid = (unsigned)s < (unsigned)LIN;
            size_t o = ((size_t)b * LIN + (valid ? s : 0)) * CIN + c0 + lg * 8;
            const half8* ph = (const half8*)(xth + o);
            const half8* pl = (const half8*)(xtl + o);
            #pragma unroll
            for (int kc = 0; kc < 4; ++kc) {
                half8 vh = {}, vl = {};
                if (valid) { vh = ph[kc * 4]; vl = pl[kc * 4]; }
                ah[g][kc] = vh; al[g][kc] = vl;
            }
        }
        if (t < 8) stage(t + 1, buf ^ 1);
        const char* bhp = smem + buf * 65536;
        const char* blp = bhp + 32768;
        #pragma unroll
        for (int kc = 0; kc < 4; ++kc) {
            half8 bhf[2], blf[2];
            #pragma unroll
            for (int cg = 0; cg < 2; ++cg) {
                int col   = cgw * 32 + cg * 16 + lr;
                int kswz  = (col & 7) << 4;
                int cbyte = col * 256;
                int kb    = (kc * 64 + lg * 16) ^ kswz;
                bhf[cg] = *(const half8*)(bhp + cbyte + kb);
                blf[cg] = *(const half8*)(blp + cbyte + kb);
            }
            #pragma unroll
            for (int cg = 0; cg < 2; ++cg)
                #pragma unroll
                for (int g = 0; g < 2; ++g)
                    acc[g][cg] = __builtin_amdgcn_mfma_f32_16x16x32_f16(ah[g][kc], bhf[cg], acc[g][cg], 0, 0, 0);
            #pragma unroll
            for (int cg = 0; cg < 2; ++cg)
                #pragma unroll
                for (int g = 0; g < 2; ++g)
                    acc[g][cg] = __builtin_amdgcn_mfma_f32_16x16x32_f16(al[g][kc], bhf[cg], acc[g][cg], 0, 0, 0);
            #pragma unroll
            for (int cg = 0; cg < 2; ++cg)
                #pragma unroll
                for (int g = 0; g < 2; ++g)
                    acc[g][cg] = __builtin_amdgcn_mfma_f32_16x16x32_f16(ah[g][kc], blf[cg], acc[g][cg], 0, 0, 0);
        }
        __syncthreads();
        buf ^= 1;
    }

    float* pb = part + (size_t)ks * NROWS * DCODE;
    #pragma unroll
    for (int g = 0; g < 2; ++g)
        #pragma unroll
        for (int cg = 0; cg < 2; ++cg) {
            int col = cgw * 32 + cg * 16 + lr;
            #pragma unroll
            for (int rr = 0; rr < 4; ++rr) {
                int row = r0 + rg * 32 + g * 16 + lg * 4 + rr;
                pb[(size_t)row * DCODE + col] = acc[g][cg][rr];
            }
        }
}

// ---------------------------------------------------------------------------
// Combine K-halves + L2-normalize encodings -> fp16 hi/lo split.
__global__ __launch_bounds__(256) void k_encnorm(const float* __restrict__ part,
                                                 half_t* __restrict__ eh,
                                                 half_t* __restrict__ el) {
    int wid  = threadIdx.x >> 6;
    int lane = threadIdx.x & 63;
    int r = blockIdx.x * 4 + wid;
    const float2* p0 = (const float2*)part + (size_t)r * 64;
    const float2* p1 = (const float2*)(part + (size_t)NROWS * DCODE) + (size_t)r * 64;
    float2 a = p0[lane];
    float2 c = p1[lane];
    a.x += c.x; a.y += c.y;
    float ss = a.x * a.x + a.y * a.y;
    #pragma unroll
    for (int m = 1; m < 64; m <<= 1) ss += __shfl_xor(ss, m);
    float inv = 1.0f / fmaxf(sqrtf(ss), EPS);
    float nx = a.x * inv, ny = a.y * inv;
    half_t hx = (half_t)nx, hy = (half_t)ny;
    half_t lx = (half_t)(nx - (float)hx), ly = (half_t)(ny - (float)hy);
    ((half2v*)eh)[(size_t)r * 64 + lane] = half2v{hx, hy};
    ((half2v*)el)[(size_t)r * 64 + lane] = half2v{lx, ly};
}

// ---------------------------------------------------------------------------
// MFMA dist+argmax — round-9: counted-vmcnt pipeline (T4). 512 thr, 8 waves =
// 2 row-groups x 4 col-groups (A = 64 VGPR/wave, stays resident). Raw
// s_barrier + vmcnt(8) — loads for tile t+1 stay in flight across the whole
// compute of tile t; no vmcnt(0) drain in the main loop. cn2 slice preloaded
// into LDS so no stray global loads perturb the vmcnt count.
__global__ __launch_bounds__(512, 2) void k_dist(const half_t* __restrict__ eh,
                                                 const half_t* __restrict__ el,
                                                 const half_t* __restrict__ ch,
                                                 const half_t* __restrict__ cl,
                                                 const float* __restrict__ cn2,
                                                 float* __restrict__ best_s,
                                                 int* __restrict__ best_i) {
    extern __shared__ char smem[];          // 128KB dbuf + 16KB cn2
    const int tid  = threadIdx.x;
    const int lane = tid & 63;
    const int w    = tid >> 6;              // 0..7
    const int rg   = w >> 2;                // row-group (32 rows)
    const int cgw  = w & 3;                 // col-group (32 cols)
    const int lr   = lane & 15;
    const int lg   = lane >> 4;
    const int r0   = blockIdx.x * 64;
    const int kqbase = blockIdx.y * 4096;

    float* cnS = (float*)(smem + 131072);
    for (int i = tid; i < 1024; i += 512)
        ((float4*)cnS)[i] = ((const float4*)(cn2 + kqbase))[i];

    // A: rows r0 + rg*32 + g*16 + lr  (64 VGPR total)
    half8 ah[2][4], al[2][4];
    #pragma unroll
    for (int g = 0; g < 2; ++g) {
        int row = r0 + rg * 32 + g * 16 + lr;
        const half8* ph = (const half8*)(eh + (size_t)row * 128 + lg * 8);
        const half8* pl = (const half8*)(el + (size_t)row * 128 + lg * 8);
        #pragma unroll
        for (int kc = 0; kc < 4; ++kc) { ah[g][kc] = ph[kc * 4]; al[g][kc] = pl[kc * 4]; }
    }

    // staging: waves 0-3 stage hi (32 cols each), 4-7 stage lo; 8 loads/wave
    const half_t* msrc = (w >= 4) ? cl : ch;
    const int wmod = w & 3;
    auto stage = [&](int t, int buf) {
        #pragma unroll
        for (int i = 0; i < 8; ++i) {
            int col_l = wmod * 32 + i * 4 + lg;
            int ksrc  = (lr * 16) ^ ((col_l & 7) << 4);
            const char* g = (const char*)msrc
                          + ((size_t)(kqbase + t * 128 + col_l)) * 256 + ksrc;
            char* l = smem + buf * 65536 + (w >> 2) * 32768 + wmod * 8192
                    + i * 1024;
            __builtin_amdgcn_global_load_lds(
                (const __attribute__((address_space(1))) void*)(uintptr_t)g,
                (__attribute__((address_space(3))) void*)(uintptr_t)l, 16, 0, 0);
        }
    };

    float bs[2][4]; int bi[2][4];
    #pragma unroll
    for (int g = 0; g < 2; ++g)
        #pragma unroll
        for (int rr = 0; rr < 4; ++rr) { bs[g][rr] = -3.4e38f; bi[g][rr] = 0; }

    stage(0, 0);
    stage(1, 1);
    __syncthreads();    // one-time drain: tiles 0,1 + cnS ready

    int buf = 0;
    const int colb = cgw * 32;
    for (int t = 0; t < 32; ++t) {
        if (t >= 2) {
            // RAW gate for tile t: my 8 oldest in-flight loads (tile t) done;
            // tile t+1's 8 stay in flight.
            if (t < 31) { VMCNT(8); } else { VMCNT(0); }
            __builtin_amdgcn_s_barrier();
            __builtin_amdgcn_sched_barrier(0);
        }
        const char* bhp = smem + buf * 65536;
        const char* blp = bhp + 32768;
        f32x4 acc[2][2];
        #pragma unroll
        for (int g = 0; g < 2; ++g)
            #pragma unroll
            for (int cg = 0; cg < 2; ++cg) acc[g][cg] = f32x4{0.f, 0.f, 0.f, 0.f};
        #pragma unroll
        for (int kc = 0; kc < 4; ++kc) {
            half8 bhf[2], blf[2];
            #pragma unroll
            for (int cg = 0; cg < 2; ++cg) {
                int col = colb + cg * 16 + lr;
                int kb  = (kc * 64 + lg * 16) ^ ((col & 7) << 4);
                bhf[cg] = *(const half8*)(bhp + col * 256 + kb);
                blf[cg] = *(const half8*)(blp + col * 256 + kb);
            }
            #pragma unroll
            for (int cg = 0; cg < 2; ++cg)
                #pragma unroll
                for (int g = 0; g < 2; ++g)
                    acc[g][cg] = __builtin_amdgcn_mfma_f32_16x16x32_f16(ah[g][kc], bhf[cg], acc[g][cg], 0, 0, 0);
            #pragma unroll
            for (int cg = 0; cg < 2; ++cg)
                #pragma unroll
                for (int g = 0; g < 2; ++g)
                    acc[g][cg] = __builtin_amdgcn_mfma_f32_16x16x32_f16(al[g][kc], bhf[cg], acc[g][cg], 0, 0, 0);
            #pragma unroll
            for (int cg = 0; cg < 2; ++cg)
                #pragma unroll
                for (int g = 0; g < 2; ++g)
                    acc[g][cg] = __builtin_amdgcn_mfma_f32_16x16x32_f16(ah[g][kc], blf[cg], acc[g][cg], 0, 0, 0);
        }
        #pragma unroll
        for (int g = 0; g < 2; ++g)
            #pragma unroll
            for (int cg = 0; cg < 2; ++cg) {
                float cnv = cnS[t * 128 + colb + cg * 16 + lr];
                int n = kqbase + t * 128 + colb + cg * 16 + lr;
                #pragma unroll
                for (int rr = 0; rr < 4; ++rr) {
                    float sc = 2.0f * acc[g][cg][rr] - cnv;
                    if (sc > bs[g][rr]) { bs[g][rr] = sc; bi[g][rr] = n; }
                }
            }
        __builtin_amdgcn_s_barrier();          // WAR: everyone done with buf
        if (t + 2 < 32) stage(t + 2, buf);     // refill just-freed buffer
        buf ^= 1;
    }

    // reduce over 16 lr lanes, then across the 4 col-group waves per row-group
    float* redS = (float*)smem;            // [8][32]
    int*   redI = (int*)(smem + 1024);     // [8][32]
    #pragma unroll
    for (int g = 0; g < 2; ++g)
        #pragma unroll
        for (int rr = 0; rr < 4; ++rr) {
            float s = bs[g][rr]; int i = bi[g][rr];
            #pragma unroll
            for (int m = 1; m < 16; m <<= 1) {
                float os = __shfl_xor(s, m);
                int   oi = __shfl_xor(i, m);
                if (os > s || (os == s && oi < i)) { s = os; i = oi; }
            }
            if (lr == 0) {
                int rloc = g * 16 + lg * 4 + rr;     // 0..31 within row-group
                redS[w * 32 + rloc] = s;
                redI[w * 32 + rloc] = i;
            }
        }
    __syncthreads();
    if (tid < 64) {
        int rgg = tid >> 5, rloc = tid & 31;
        float s = redS[(rgg * 4) * 32 + rloc];
        int   i = redI[(rgg * 4) * 32 + rloc];
        #pragma unroll
        for (int j = 1; j < 4; ++j) {
            float s2 = redS[(rgg * 4 + j) * 32 + rloc];
            int   i2 = redI[(rgg * 4 + j) * 32 + rloc];
            if (s2 > s || (s2 == s && i2 < i)) { s = s2; i = i2; }
        }
        best_s[(size_t)blockIdx.y * NROWS + r0 + tid] = s;
        best_i[(size_t)blockIdx.y * NROWS + r0 + tid] = i;
    }
}

// ---------------------------------------------------------------------------
__global__ __launch_bounds__(256) void k_merge(const float* __restrict__ bs,
                                               const int* __restrict__ bi,
                                               int* __restrict__ out) {
    int r = blockIdx.x * 256 + threadIdx.x;
    if (r >= NROWS) return;
    float s = bs[r]; int i = bi[r];
    #pragma unroll
    for (int q = 1; q < 2; ++q) {
        float s2 = bs[(size_t)q * NROWS + r];
        int   i2 = bi[(size_t)q * NROWS + r];
        if (s2 > s || (s2 == s && i2 < i)) { s = s2; i = i2; }
    }
    out[r] = i;
}

// ---------------------------------------------------------------------------
extern "C" void kernel_launch(void* const* d_in, const int* in_sizes, int n_in,
                              void* d_out, int out_size, void* d_ws, size_t ws_size,
                              hipStream_t stream) {
    const float* x  = (const float*)d_in[0];
    const float* w  = (const float*)d_in[1];
    const float* cb = (const float*)d_in[2];
    char* ws = (char*)d_ws;
    float*  cn2  = (float*)(ws + OFF_CN2);
    float*  bs   = (float*)(ws + OFF_BS);
    int*    bi   = (int*)(ws + OFF_BI);
    half_t* eh   = (half_t*)(ws + OFF_EH);
    half_t* el   = (half_t*)(ws + OFF_EL);
    half_t* chh  = (half_t*)(ws + OFF_CH);
    half_t* cll  = (half_t*)(ws + OFF_CL);
    half_t* wht  = (half_t*)(ws + OFF_WHT);
    half_t* wlt  = (half_t*)(ws + OFF_WLT);
    float*  part = (float*)(ws + OFF_PART);
    half_t* xth  = (half_t*)(ws + OFF_XTH);
    half_t* xtl  = (half_t*)(ws + OFF_XTL);
    int*    out  = (int*)d_out;

    hipFuncSetAttribute((const void*)k_dist,
                        hipFuncAttributeMaxDynamicSharedMemorySize, 147456);
    hipFuncSetAttribute((const void*)k_conv_mfma,
                        hipFuncAttributeMaxDynamicSharedMemorySize, 131072);

    k_wt2     <<<dim3(9, 128), 256, 0, stream>>>(w, wht, wlt);
    k_cbnorm  <<<2048, 256, 0, stream>>>(cb, chh, cll, cn2);
    k_xt      <<<dim3(64, 6, 4), 256, 0, stream>>>(x, xth, xtl);
    k_conv_mfma<<<dim3(128, 2), 512, 131072, stream>>>(xth, xtl, wht, wlt, part);
    k_encnorm <<<2048, 256, 0, stream>>>(part, eh, el);
    k_dist    <<<dim3(128, 2), 512, 147456, stream>>>(eh, el, chh, cll, cn2, bs, bi);
    k_merge   <<<32, 256, 0, stream>>>(bs, bi, out);
}